// Round 3
// baseline (355.893 us; speedup 1.0000x reference)
//
#include <hip/hip_runtime.h>
#include <hip/hip_bf16.h>

#define BB 4
#define TT 4096
#define CC 1024
#define HH 64

typedef _Float16 f16;
typedef __attribute__((ext_vector_type(8))) _Float16 f16x8;
typedef __attribute__((ext_vector_type(4))) _Float16 f16x4;
typedef __attribute__((ext_vector_type(4))) float f32x4;

#define MFMA32(a,b,c) __builtin_amdgcn_mfma_f32_16x16x32_f16((a),(b),(c),0,0,0)
#define MFMA16(a,b,c) __builtin_amdgcn_mfma_f32_16x16x16f16((a),(b),(c),0,0,0)

static __device__ __forceinline__ f16x8 pack2(f32x4 a, f32x4 b) {
  f16x8 r;
  r[0]=(f16)a[0]; r[1]=(f16)a[1]; r[2]=(f16)a[2]; r[3]=(f16)a[3];
  r[4]=(f16)b[0]; r[5]=(f16)b[1]; r[6]=(f16)b[2]; r[7]=(f16)b[3];
  return r;
}

// ---------------------------------------------------------------------------
// Projection: X[16384,1024] fp32 x W^T -> f16 [16384,64].
// LDS-free, barrier-free main loop: A-frags and B-frags read DIRECTLY from
// global in MFMA layout (8 consecutive fp32 per lane), cvt to f16 in regs.
// 1-deep register prefetch. Grid (256,3) = 768 blocks, 12 waves/CU.
// V path only: LDS transpose epilogue -> Vth [B][64][T].
// ---------------------------------------------------------------------------
__global__ __launch_bounds__(256) void proj_kernel(
    const float* __restrict__ qg, const float* __restrict__ kg, const float* __restrict__ vg,
    const float* __restrict__ Wqg, const float* __restrict__ Wkg, const float* __restrict__ Wvg,
    f16* __restrict__ Qh, f16* __restrict__ Kh, f16* __restrict__ Vth)
{
  __shared__ f16 Vs[64][72];   // V-transpose epilogue only

  const float* X; const float* W; f16* O; int tr;
  if (blockIdx.y == 0)      { X = qg; W = Wqg; O = Qh;  tr = 0; }
  else if (blockIdx.y == 1) { X = kg; W = Wkg; O = Kh;  tr = 0; }
  else                      { X = vg; W = Wvg; O = Vth; tr = 1; }

  const int tid  = threadIdx.x;
  const int wave = tid >> 6;
  const int lane = tid & 63;
  const int quad = lane >> 4;
  const int l16  = lane & 15;
  const int row0 = blockIdx.x * 64 + wave * 16;

  const float* Ap = X + (size_t)(row0 + l16) * CC + quad * 8;  // A: m=l16, k=quad*8+j
  const float* Wp = W + (size_t)l16 * CC + quad * 8;           // B: n=l16, k=quad*8+j

  f32x4 acc[4];
  #pragma unroll
  for (int nt = 0; nt < 4; ++nt) acc[nt] = (f32x4){0.f, 0.f, 0.f, 0.f};

  f32x4 a[2], w[4][2];
  a[0] = *(const f32x4*)(Ap);
  a[1] = *(const f32x4*)(Ap + 4);
  #pragma unroll
  for (int nt = 0; nt < 4; ++nt) {
    w[nt][0] = *(const f32x4*)(Wp + nt * 16 * CC);
    w[nt][1] = *(const f32x4*)(Wp + nt * 16 * CC + 4);
  }

  #pragma unroll 1
  for (int it = 0; it < 31; ++it) {
    const int ko = (it + 1) * 32;
    f32x4 na[2], nw[4][2];
    na[0] = *(const f32x4*)(Ap + ko);
    na[1] = *(const f32x4*)(Ap + ko + 4);
    #pragma unroll
    for (int nt = 0; nt < 4; ++nt) {
      nw[nt][0] = *(const f32x4*)(Wp + nt * 16 * CC + ko);
      nw[nt][1] = *(const f32x4*)(Wp + nt * 16 * CC + ko + 4);
    }
    f16x8 af = pack2(a[0], a[1]);
    #pragma unroll
    for (int nt = 0; nt < 4; ++nt)
      acc[nt] = MFMA32(af, pack2(w[nt][0], w[nt][1]), acc[nt]);
    a[0] = na[0]; a[1] = na[1];
    #pragma unroll
    for (int nt = 0; nt < 4; ++nt) { w[nt][0] = nw[nt][0]; w[nt][1] = nw[nt][1]; }
  }
  {
    f16x8 af = pack2(a[0], a[1]);
    #pragma unroll
    for (int nt = 0; nt < 4; ++nt)
      acc[nt] = MFMA32(af, pack2(w[nt][0], w[nt][1]), acc[nt]);
  }

  if (!tr) {
    // C/D: row = quad*4+r (X row), col = l16 (+nt*16) (head dim)
    #pragma unroll
    for (int nt = 0; nt < 4; ++nt)
      #pragma unroll
      for (int r = 0; r < 4; ++r)
        O[(size_t)(row0 + quad * 4 + r) * HH + nt * 16 + l16] = (f16)acc[nt][r];
  } else {
    // transpose 64x64 tile through LDS, coalesced f16x8 stores
    #pragma unroll
    for (int nt = 0; nt < 4; ++nt) {
      f16x4 v4;
      #pragma unroll
      for (int r = 0; r < 4; ++r) v4[r] = (f16)acc[nt][r];
      *(f16x4*)&Vs[nt * 16 + l16][wave * 16 + quad * 4] = v4;
    }
    __syncthreads();
    const int r0 = blockIdx.x * 64;
    const int b = r0 >> 12, t0 = r0 & (TT - 1);
    const int lrow = tid >> 2;
    const int lcol = (tid & 3) * 16;
    f16x8 o0 = *(const f16x8*)&Vs[lrow][lcol];
    f16x8 o1 = *(const f16x8*)&Vs[lrow][lcol + 8];
    *(f16x8*)(O + (size_t)(b * HH + lrow) * TT + t0 + lcol)     = o0;
    *(f16x8*)(O + (size_t)(b * HH + lrow) * TT + t0 + lcol + 8) = o1;
  }
}

// ---------------------------------------------------------------------------
// Flash attention, mask s <= t+1, softmax(QK^T / 64). LDS/barrier-free.
// S^T via MFMA(A=K,B=Q): C-layout (col=query,row=key) == A-layout of
// mfma_16x16x16f16 -> P feeds PV with no transpose.
// No online max (scores/64 bounded ~ +-1 -> exp2 safe, verified R2).
// Pipelined: exact per-wave trip count + 1-deep K-register prefetch.
// Pair-fold (j,63-j) + S-way key split.
// ---------------------------------------------------------------------------
__device__ __forceinline__ void attn_tile(
    int b, int j, int a, int e, int wave, int quad, int l16, int sp,
    const f16* __restrict__ Qh, const f16* __restrict__ Kh, const f16* __restrict__ Vth,
    float* __restrict__ Opart, float* __restrict__ lpart)
{
  const int m0 = j * 64 + wave * 16;
  const float SC2 = 1.4426950408889634f / 64.0f;   // log2(e)/64 (double scaling)
  const int e_w = min(e, j + 1 + (wave == 3 ? 1 : 0));  // keys needed: s0 <= m0+16

  const f16* qp = Qh + (size_t)(b * TT + m0 + l16) * HH + quad * 8;
  f16x8 qa0 = *(const f16x8*)qp;          // B-frag: hd 0..31
  f16x8 qa1 = *(const f16x8*)(qp + 32);   // hd 32..63

  const f16* kbase = Kh + ((size_t)b * TT + l16) * HH + quad * 8;
  const f16* vbase = Vth + (size_t)(b * HH + l16) * TT + quad * 4;

  f32x4 o[4];
  float lsum = 0.f;
  #pragma unroll
  for (int nt = 0; nt < 4; ++nt) o[nt] = (f32x4){0.f, 0.f, 0.f, 0.f};

  f16x8 kc[8];
  int st = a;
  if (st < e_w) {
    const f16* kp = kbase + (size_t)st * 64 * HH;
    #pragma unroll
    for (int ct = 0; ct < 4; ++ct) {
      kc[2 * ct]     = *(const f16x8*)(kp + ct * 16 * HH);
      kc[2 * ct + 1] = *(const f16x8*)(kp + ct * 16 * HH + 32);
    }
  }

  while (st < e_w) {
    const int s0 = st * 64;
    // V loads for this step (consumed after exp2 -- latency covered)
    f16x4 vc[4][4];
    const f16* vp = vbase + s0;
    #pragma unroll
    for (int ct = 0; ct < 4; ++ct)
      #pragma unroll
      for (int nt = 0; nt < 4; ++nt)
        vc[ct][nt] = *(const f16x4*)(vp + (size_t)nt * 16 * TT + ct * 16);

    // prefetch next step's K
    const bool more = (st + 1 < e_w);
    f16x8 kn[8];
    if (more) {
      const f16* kp = kbase + (size_t)(st + 1) * 64 * HH;
      #pragma unroll
      for (int ct = 0; ct < 4; ++ct) {
        kn[2 * ct]     = *(const f16x8*)(kp + ct * 16 * HH);
        kn[2 * ct + 1] = *(const f16x8*)(kp + ct * 16 * HH + 32);
      }
    }

    // S^T = K Q^T
    f32x4 sc[4];
    #pragma unroll
    for (int ct = 0; ct < 4; ++ct) {
      f32x4 z = (f32x4){0.f, 0.f, 0.f, 0.f};
      z = MFMA32(kc[2 * ct], qa0, z);
      sc[ct] = MFMA32(kc[2 * ct + 1], qa1, z);
    }

    // scale, mask, exp2; lane: query = m0+l16, key = s0+ct*16+quad*4+r
    const bool domask = (s0 + 63) > (m0 + 1);
    f16x4 pa[4];
    #pragma unroll
    for (int ct = 0; ct < 4; ++ct) {
      #pragma unroll
      for (int r = 0; r < 4; ++r) {
        float x = sc[ct][r] * SC2;
        if (domask) {
          const int key = s0 + ct * 16 + quad * 4 + r;
          if (key > m0 + l16 + 1) x = -__builtin_inff();
        }
        const float pv = __builtin_amdgcn_exp2f(x);
        lsum += pv;
        pa[ct][r] = (f16)pv;
      }
    }

    // PV: A=P, B=V
    #pragma unroll
    for (int ct = 0; ct < 4; ++ct)
      #pragma unroll
      for (int nt = 0; nt < 4; ++nt)
        o[nt] = MFMA16(pa[ct], vc[ct][nt], o[nt]);

    if (more) {
      #pragma unroll
      for (int i = 0; i < 8; ++i) kc[i] = kn[i];
    }
    ++st;
  }

  // l over quads; lane's lsum covers its key subset for query l16
  lsum += __shfl_xor(lsum, 16, 64);
  lsum += __shfl_xor(lsum, 32, 64);
  const size_t rbase = (size_t)(sp * BB + b) * TT;
  if (quad == 0) lpart[rbase + m0 + l16] = lsum;
  #pragma unroll
  for (int nt = 0; nt < 4; ++nt)
    #pragma unroll
    for (int r = 0; r < 4; ++r)
      Opart[(rbase + m0 + quad * 4 + r) * HH + nt * 16 + l16] = o[nt][r];
}

__global__ __launch_bounds__(256) void attn_kernel(
    const f16* __restrict__ Qh, const f16* __restrict__ Kh, const f16* __restrict__ Vth,
    float* __restrict__ Opart, float* __restrict__ lpart, int S)
{
  const int pr = blockIdx.x;   // fold pair 0..31
  const int sp = blockIdx.y;   // key split 0..S-1
  const int b  = blockIdx.z;
  const int tid  = threadIdx.x;
  const int wave = tid >> 6;
  const int lane = tid & 63;
  const int quad = lane >> 4;
  const int l16  = lane & 15;

  const int j1 = pr, j2 = 63 - pr;
  const int n1 = min(j1 + 2, 64), n2 = min(j2 + 2, 64);
  const int tot = n1 + n2;                       // ~67, balanced across pairs
  const int lo = tot * sp / S, hi = tot * (sp + 1) / S;
  const int a1 = min(lo, n1), e1 = min(hi, n1);
  const int a2 = max(lo - n1, 0), e2 = max(hi - n1, 0);

  attn_tile(b, j1, a1, e1, wave, quad, l16, sp, Qh, Kh, Vth, Opart, lpart);
  attn_tile(b, j2, a2, e2, wave, quad, l16, sp, Qh, Kh, Vth, Opart, lpart);
}

// ---------------------------------------------------------------------------
// Combine S split partials: out = sum_s O_s / sum_s l_s
// ---------------------------------------------------------------------------
__global__ __launch_bounds__(256) void combine_kernel(
    const float* __restrict__ Opart, const float* __restrict__ lpart,
    float* __restrict__ out, int S)
{
  const int idx = blockIdx.x * 256 + threadIdx.x;   // 0..262143
  const int row = idx >> 4;                         // 0..16383
  const int c   = (idx & 15) * 4;
  float l = 0.f;
  f32x4 s = (f32x4){0.f, 0.f, 0.f, 0.f};
  for (int p = 0; p < S; ++p) {
    l += lpart[(size_t)p * BB * TT + row];
    s += *(const f32x4*)&Opart[((size_t)p * BB * TT + row) * HH + c];
  }
  const float inv = 1.0f / l;
  *(f32x4*)&out[(size_t)row * HH + c] = s * inv;
}

// ---------------------------------------------------------------------------
extern "C" void kernel_launch(void* const* d_in, const int* in_sizes, int n_in,
                              void* d_out, int out_size, void* d_ws, size_t ws_size,
                              hipStream_t stream)
{
  const float* q  = (const float*)d_in[0];
  const float* k  = (const float*)d_in[1];
  const float* v  = (const float*)d_in[2];
  const float* Wq = (const float*)d_in[3];
  const float* Wk = (const float*)d_in[4];
  const float* Wv = (const float*)d_in[5];
  float* out = (float*)d_out;

  const size_t n = (size_t)BB * TT * HH;   // 1,048,576
  // splits: prefer 8-way (needs ~38.5 MB ws); fall back to 4 (22.3 MB, known OK)
  const size_t need8 = 3 * n * sizeof(f16) + 8 * n * sizeof(float) + 8 * (size_t)BB * TT * sizeof(float);
  const int S = (ws_size >= need8) ? 8 : 4;

  f16* Qh  = (f16*)d_ws;
  f16* Kh  = Qh + n;
  f16* Vth = Kh + n;                 // transposed [B][64][T]
  float* Opart = (float*)(Vth + n);  // [S][B][T][64] fp32
  float* lpart = Opart + (size_t)S * n;  // [S][B][T] fp32

  proj_kernel<<<dim3(256, 3), 256, 0, stream>>>(q, k, v, Wq, Wk, Wv, Qh, Kh, Vth);
  attn_kernel<<<dim3(32, S, BB), 256, 0, stream>>>(Qh, Kh, Vth, Opart, lpart, S);
  combine_kernel<<<dim3(1024), 256, 0, stream>>>(Opart, lpart, out, S);
}

// Round 4
// 252.910 us; speedup vs baseline: 1.4072x; 1.4072x over previous
//
#include <hip/hip_runtime.h>
#include <hip/hip_bf16.h>

#define BB 4
#define TT 4096
#define CC 1024
#define HH 64

typedef _Float16 f16;
typedef __attribute__((ext_vector_type(8))) _Float16 f16x8;
typedef __attribute__((ext_vector_type(4))) _Float16 f16x4;
typedef __attribute__((ext_vector_type(4))) float f32x4;

#define MFMA32(a,b,c) __builtin_amdgcn_mfma_f32_16x16x32_f16((a),(b),(c),0,0,0)
#define MFMA16(a,b,c) __builtin_amdgcn_mfma_f32_16x16x16f16((a),(b),(c),0,0,0)

// frag-major sizes (f16 units)
#define WF_ELEMS (3 * 32 * 4 * 64 * 8)        // 196,608
#define CHUNK_F16 1024                        // per 16-row chunk: 2 halves x 64 lanes x 8
#define PB_F16 (256 * CHUNK_F16)              // per batch: 256 chunks

// ---------------------------------------------------------------------------
// Repack W -> frag-major f16. Block bx = (p*32+kc)*4+nt, 64 threads.
// Wf[p][kc][nt][lane][j] = W_p[nt*16 + l16][kc*32 + quad*8 + j]
// Softmax double-scale log2(e)/64 folded into Wq.
// ---------------------------------------------------------------------------
__global__ __launch_bounds__(64) void wrepack_kernel(
    const float* __restrict__ Wqg, const float* __restrict__ Wkg,
    const float* __restrict__ Wvg, f16* __restrict__ Wf)
{
  const int bx = blockIdx.x;
  const int nt = bx & 3;
  const int kc = (bx >> 2) & 31;
  const int p  = bx >> 7;
  const float* W = (p == 0) ? Wqg : (p == 1) ? Wkg : Wvg;
  const float sc = (p == 0) ? (1.4426950408889634f / 64.0f) : 1.0f;

  const int lane = threadIdx.x;
  const int l16 = lane & 15, quad = lane >> 4;
  const float* src = W + (size_t)(nt * 16 + l16) * CC + kc * 32 + quad * 8;
  f32x4 a = *(const f32x4*)src;
  f32x4 b = *(const f32x4*)(src + 4);
  f16x8 r;
  #pragma unroll
  for (int j = 0; j < 4; ++j) { r[j] = (f16)(a[j] * sc); r[j + 4] = (f16)(b[j] * sc); }
  *(f16x8*)(Wf + (size_t)bx * 512 + lane * 8) = r;
}

// ---------------------------------------------------------------------------
// Projection: X[16384,1024] fp32 x W^T -> frag-major f16 outputs.
// Wave-private LDS A-staging (coalesced 256-B segments), NO __syncthreads in
// main loop. W-frags coalesced from L2-hot Wf. Grid (256,3), 256 thr.
// ---------------------------------------------------------------------------
__global__ __launch_bounds__(256) void proj_kernel(
    const float* __restrict__ qg, const float* __restrict__ kg, const float* __restrict__ vg,
    const f16* __restrict__ Wf,
    f16* __restrict__ Qf, f16* __restrict__ Kf, f16* __restrict__ Vf)
{
  __shared__ f16 As[4][2][16][66];   // [wave][buf][row][col] wave-private

  const float* X; f16* O; int p = blockIdx.y;
  if (p == 0)      { X = qg; O = Qf; }
  else if (p == 1) { X = kg; O = Kf; }
  else             { X = vg; O = Vf; }

  const int tid  = threadIdx.x;
  const int w    = tid >> 6;
  const int lane = tid & 63;
  const int quad = lane >> 4;
  const int l16  = lane & 15;
  const int r0   = blockIdx.x * 64 + w * 16;

  const float* Xp = X + (size_t)(r0 + (lane >> 4)) * CC + (lane & 15) * 4;
  const f16* Wbase = Wf + (size_t)p * 32 * 4 * 512 + lane * 8;

  f32x4 acc[4];
  #pragma unroll
  for (int nt = 0; nt < 4; ++nt) acc[nt] = (f32x4){0.f, 0.f, 0.f, 0.f};

  f32x4 cur[4], nxt[4];
  #pragma unroll
  for (int j = 0; j < 4; ++j) cur[j] = *(const f32x4*)(Xp + (size_t)(j * 4) * CC);

  #pragma unroll 1
  for (int it = 0; it < 16; ++it) {
    const int buf = it & 1;
    // stage current 64-col window (wave-private, f16)
    #pragma unroll
    for (int j = 0; j < 4; ++j) {
      f16x4 h;
      #pragma unroll
      for (int t = 0; t < 4; ++t) h[t] = (f16)cur[j][t];
      *(f16x4*)&As[w][buf][j * 4 + (lane >> 4)][(lane & 15) * 4] = h;
    }
    // prefetch next window
    if (it < 15) {
      const int c0 = (it + 1) * 64;
      #pragma unroll
      for (int j = 0; j < 4; ++j)
        nxt[j] = *(const f32x4*)(Xp + (size_t)(j * 4) * CC + c0);
    }
    // W frags for this window (L2-hot, coalesced)
    f16x8 wf[2][4];
    #pragma unroll
    for (int kk = 0; kk < 2; ++kk)
      #pragma unroll
      for (int nt = 0; nt < 4; ++nt)
        wf[kk][nt] = *(const f16x8*)(Wbase + (size_t)((it * 2 + kk) * 4 + nt) * 512);
    // MFMAs
    #pragma unroll
    for (int kk = 0; kk < 2; ++kk) {
      f16x8 af = *(const f16x8*)&As[w][buf][l16][kk * 32 + quad * 8];
      #pragma unroll
      for (int nt = 0; nt < 4; ++nt)
        acc[nt] = MFMA32(af, wf[kk][nt], acc[nt]);
    }
    #pragma unroll
    for (int j = 0; j < 4; ++j) cur[j] = nxt[j];
  }

  // epilogue: acc (C-layout: row=quad*4+r, col=nt*16+l16) -> frag-major via
  // wave-private LDS transpose. chunk = global 16-row index.
  f16 (*Ls)[66] = As[w][0];
  #pragma unroll
  for (int nt = 0; nt < 4; ++nt)
    #pragma unroll
    for (int r = 0; r < 4; ++r)
      Ls[quad * 4 + r][nt * 16 + l16] = (f16)acc[nt][r];
  const size_t chunk = (size_t)blockIdx.x * 4 + w;
  if (p < 2) {
    // Q/K frag: [chunk][half][lane][8] = tile[row=l16][hd=32h+8q+j]
    #pragma unroll
    for (int h = 0; h < 2; ++h) {
      f16x8 t = *(const f16x8*)&Ls[l16][h * 32 + quad * 8];
      *(f16x8*)(O + (chunk * 2 + h) * 512 + lane * 8) = t;
    }
  } else {
    // V frag: [chunk][np][lane][8] = tile[key=4q+(j&3)][hd=(2np+(j>>2))*16+l16]
    #pragma unroll
    for (int np = 0; np < 2; ++np) {
      f16x8 t;
      #pragma unroll
      for (int j = 0; j < 8; ++j)
        t[j] = Ls[quad * 4 + (j & 3)][(2 * np + (j >> 2)) * 16 + l16];
      *(f16x8*)(O + (chunk * 2 + np) * 512 + lane * 8) = t;
    }
  }
}

// ---------------------------------------------------------------------------
// Flash attention, mask s <= t+1. All frag loads coalesced (frag-major).
// S^T via MFMA(A=K,B=Q); P C-layout == MFMA16 A-layout (no transpose).
// Scale pre-folded into Wq. Pair-fold + S-way key split.
// ---------------------------------------------------------------------------
__device__ __forceinline__ void attn_tile(
    int b, int j, int a, int e, int wave, int quad, int l16, int lane, int sp,
    const f16* __restrict__ Qf, const f16* __restrict__ Kf, const f16* __restrict__ Vf,
    float* __restrict__ Opart, float* __restrict__ lpart)
{
  const int m0 = j * 64 + wave * 16;
  const int e_w = min(e, j + 1 + (wave == 3 ? 1 : 0));

  const f16* Qfb = Qf + (size_t)b * PB_F16;
  const f16* Kfb = Kf + (size_t)b * PB_F16 + lane * 8;
  const f16* Vfb = Vf + (size_t)b * PB_F16 + lane * 8;

  f16x8 qa0 = *(const f16x8*)(Qfb + ((size_t)(m0 >> 4) * 2 + 0) * 512 + lane * 8);
  f16x8 qa1 = *(const f16x8*)(Qfb + ((size_t)(m0 >> 4) * 2 + 1) * 512 + lane * 8);

  f32x4 o[4];
  float lsum = 0.f;
  #pragma unroll
  for (int nt = 0; nt < 4; ++nt) o[nt] = (f32x4){0.f, 0.f, 0.f, 0.f};

  f16x8 kc[8];
  int st = a;
  if (st < e_w) {
    const f16* kp = Kfb + (size_t)st * 4 * CHUNK_F16;
    #pragma unroll
    for (int ct = 0; ct < 4; ++ct) {
      kc[2 * ct]     = *(const f16x8*)(kp + ct * CHUNK_F16);
      kc[2 * ct + 1] = *(const f16x8*)(kp + ct * CHUNK_F16 + 512);
    }
  }

  while (st < e_w) {
    const int s0 = st * 64;
    // V for this step (coalesced; consumed after QK+softmax -> latency covered)
    f16x8 vv[4][2];
    const f16* vp = Vfb + (size_t)st * 4 * CHUNK_F16;
    #pragma unroll
    for (int ct = 0; ct < 4; ++ct) {
      vv[ct][0] = *(const f16x8*)(vp + ct * CHUNK_F16);
      vv[ct][1] = *(const f16x8*)(vp + ct * CHUNK_F16 + 512);
    }
    // prefetch next step's K
    const bool more = (st + 1 < e_w);
    f16x8 kn[8];
    if (more) {
      const f16* kp = Kfb + (size_t)(st + 1) * 4 * CHUNK_F16;
      #pragma unroll
      for (int ct = 0; ct < 4; ++ct) {
        kn[2 * ct]     = *(const f16x8*)(kp + ct * CHUNK_F16);
        kn[2 * ct + 1] = *(const f16x8*)(kp + ct * CHUNK_F16 + 512);
      }
    }

    // S^T = K Q^T (scale pre-folded into Q)
    f32x4 sc[4];
    #pragma unroll
    for (int ct = 0; ct < 4; ++ct) {
      f32x4 z = (f32x4){0.f, 0.f, 0.f, 0.f};
      z = MFMA32(kc[2 * ct], qa0, z);
      sc[ct] = MFMA32(kc[2 * ct + 1], qa1, z);
    }

    // mask + exp2; lane: query=m0+l16, key=s0+ct*16+quad*4+r
    const bool domask = (s0 + 63) > (m0 + 1);
    f16x4 pa[4];
    #pragma unroll
    for (int ct = 0; ct < 4; ++ct) {
      #pragma unroll
      for (int r = 0; r < 4; ++r) {
        float x = sc[ct][r];
        if (domask) {
          const int key = s0 + ct * 16 + quad * 4 + r;
          if (key > m0 + l16 + 1) x = -__builtin_inff();
        }
        const float pv = __builtin_amdgcn_exp2f(x);
        lsum += pv;
        pa[ct][r] = (f16)pv;
      }
    }

    // PV: A=P (MFMA16 A-layout), B=V frag halves
    #pragma unroll
    for (int ct = 0; ct < 4; ++ct) {
      #pragma unroll
      for (int np = 0; np < 2; ++np) {
        f16x4 blo = __builtin_shufflevector(vv[ct][np], vv[ct][np], 0, 1, 2, 3);
        f16x4 bhi = __builtin_shufflevector(vv[ct][np], vv[ct][np], 4, 5, 6, 7);
        o[2 * np]     = MFMA16(pa[ct], blo, o[2 * np]);
        o[2 * np + 1] = MFMA16(pa[ct], bhi, o[2 * np + 1]);
      }
    }

    if (more) {
      #pragma unroll
      for (int i = 0; i < 8; ++i) kc[i] = kn[i];
    }
    ++st;
  }

  lsum += __shfl_xor(lsum, 16, 64);
  lsum += __shfl_xor(lsum, 32, 64);
  const size_t rbase = (size_t)(sp * BB + b) * TT;
  if (quad == 0) lpart[rbase + m0 + l16] = lsum;
  #pragma unroll
  for (int nt = 0; nt < 4; ++nt)
    #pragma unroll
    for (int r = 0; r < 4; ++r)
      Opart[(rbase + m0 + quad * 4 + r) * HH + nt * 16 + l16] = o[nt][r];
}

__global__ __launch_bounds__(256) void attn_kernel(
    const f16* __restrict__ Qf, const f16* __restrict__ Kf, const f16* __restrict__ Vf,
    float* __restrict__ Opart, float* __restrict__ lpart, int S)
{
  const int pr = blockIdx.x;
  const int sp = blockIdx.y;
  const int b  = blockIdx.z;
  const int tid  = threadIdx.x;
  const int wave = tid >> 6;
  const int lane = tid & 63;
  const int quad = lane >> 4;
  const int l16  = lane & 15;

  const int j1 = pr, j2 = 63 - pr;
  const int n1 = min(j1 + 2, 64), n2 = min(j2 + 2, 64);
  const int tot = n1 + n2;
  const int lo = tot * sp / S, hi = tot * (sp + 1) / S;
  const int a1 = min(lo, n1), e1 = min(hi, n1);
  const int a2 = max(lo - n1, 0), e2 = max(hi - n1, 0);

  attn_tile(b, j1, a1, e1, wave, quad, l16, lane, sp, Qf, Kf, Vf, Opart, lpart);
  attn_tile(b, j2, a2, e2, wave, quad, l16, lane, sp, Qf, Kf, Vf, Opart, lpart);
}

// ---------------------------------------------------------------------------
__global__ __launch_bounds__(256) void combine_kernel(
    const float* __restrict__ Opart, const float* __restrict__ lpart,
    float* __restrict__ out, int S)
{
  const int idx = blockIdx.x * 256 + threadIdx.x;
  const int row = idx >> 4;
  const int c   = (idx & 15) * 4;
  float l = 0.f;
  f32x4 s = (f32x4){0.f, 0.f, 0.f, 0.f};
  for (int p = 0; p < S; ++p) {
    l += lpart[(size_t)p * BB * TT + row];
    s += *(const f32x4*)&Opart[((size_t)p * BB * TT + row) * HH + c];
  }
  const float inv = 1.0f / l;
  *(f32x4*)&out[(size_t)row * HH + c] = s * inv;
}

// ---------------------------------------------------------------------------
extern "C" void kernel_launch(void* const* d_in, const int* in_sizes, int n_in,
                              void* d_out, int out_size, void* d_ws, size_t ws_size,
                              hipStream_t stream)
{
  const float* q  = (const float*)d_in[0];
  const float* k  = (const float*)d_in[1];
  const float* v  = (const float*)d_in[2];
  const float* Wq = (const float*)d_in[3];
  const float* Wk = (const float*)d_in[4];
  const float* Wv = (const float*)d_in[5];
  float* out = (float*)d_out;

  const size_t n = (size_t)BB * TT * HH;   // 1,048,576 f16 per tensor
  const size_t need8 = (WF_ELEMS + 3 * n) * sizeof(f16)
                     + 8 * n * sizeof(float) + 8 * (size_t)BB * TT * sizeof(float);
  const int S = (ws_size >= need8) ? 8 : 4;

  f16* Wf = (f16*)d_ws;
  f16* Qf = Wf + WF_ELEMS;
  f16* Kf = Qf + n;
  f16* Vf = Kf + n;
  float* Opart = (float*)(Vf + n);
  float* lpart = Opart + (size_t)S * n;

  wrepack_kernel<<<dim3(384), 64, 0, stream>>>(Wq, Wk, Wv, Wf);
  proj_kernel<<<dim3(256, 3), 256, 0, stream>>>(q, k, v, Wf, Qf, Kf, Vf);
  attn_kernel<<<dim3(32, S, BB), 256, 0, stream>>>(Qf, Kf, Vf, Opart, lpart, S);
  combine_kernel<<<dim3(1024), 256, 0, stream>>>(Opart, lpart, out, S);
}

// Round 5
// 245.737 us; speedup vs baseline: 1.4483x; 1.0292x over previous
//
#include <hip/hip_runtime.h>
#include <hip/hip_bf16.h>

#define BB 4
#define TT 4096
#define CC 1024
#define HH 64

typedef _Float16 f16;
typedef __attribute__((ext_vector_type(8))) _Float16 f16x8;
typedef __attribute__((ext_vector_type(4))) _Float16 f16x4;
typedef __attribute__((ext_vector_type(4))) float f32x4;

#define MFMA32(a,b,c) __builtin_amdgcn_mfma_f32_16x16x32_f16((a),(b),(c),0,0,0)
#define MFMA16(a,b,c) __builtin_amdgcn_mfma_f32_16x16x16f16((a),(b),(c),0,0,0)

// frag-major sizes (f16 units)
#define WF_ELEMS (3 * 32 * 4 * 64 * 8)        // 196,608
#define CHUNK_F16 1024                        // per 16-row chunk: 2 halves x 64 lanes x 8
#define PB_F16 (256 * CHUNK_F16)              // per batch: 256 chunks

// ---------------------------------------------------------------------------
// Repack W -> frag-major f16. Block bx = (p*32+kc)*4+nt, 64 threads.
// Softmax double-scale log2(e)/64 folded into Wq.
// ---------------------------------------------------------------------------
__global__ __launch_bounds__(64) void wrepack_kernel(
    const float* __restrict__ Wqg, const float* __restrict__ Wkg,
    const float* __restrict__ Wvg, f16* __restrict__ Wf)
{
  const int bx = blockIdx.x;
  const int nt = bx & 3;
  const int kc = (bx >> 2) & 31;
  const int p  = bx >> 7;
  const float* W = (p == 0) ? Wqg : (p == 1) ? Wkg : Wvg;
  const float sc = (p == 0) ? (1.4426950408889634f / 64.0f) : 1.0f;

  const int lane = threadIdx.x;
  const int l16 = lane & 15, quad = lane >> 4;
  const float* src = W + (size_t)(nt * 16 + l16) * CC + kc * 32 + quad * 8;
  f32x4 a = *(const f32x4*)src;
  f32x4 b = *(const f32x4*)(src + 4);
  f16x8 r;
  #pragma unroll
  for (int j = 0; j < 4; ++j) { r[j] = (f16)(a[j] * sc); r[j + 4] = (f16)(b[j] * sc); }
  *(f16x8*)(Wf + (size_t)bx * 512 + lane * 8) = r;
}

// ---------------------------------------------------------------------------
// Projection: X[16384,1024] fp32 x W^T -> frag-major f16.
// MLP forced via 2-deep X prefetch + 1-deep W prefetch; launch_bounds(256,3)
// gives ~170 VGPR budget at 12 waves/CU. Wave-private LDS staging, no
// __syncthreads in the main loop.
// ---------------------------------------------------------------------------
__global__ __launch_bounds__(256, 3) void proj_kernel(
    const float* __restrict__ qg, const float* __restrict__ kg, const float* __restrict__ vg,
    const f16* __restrict__ Wf,
    f16* __restrict__ Qf, f16* __restrict__ Kf, f16* __restrict__ Vf)
{
  __shared__ f16 As[4][2][16][66];   // [wave][buf][row][col] wave-private

  const float* X; f16* O; int p = blockIdx.y;
  if (p == 0)      { X = qg; O = Qf; }
  else if (p == 1) { X = kg; O = Kf; }
  else             { X = vg; O = Vf; }

  const int tid  = threadIdx.x;
  const int w    = tid >> 6;
  const int lane = tid & 63;
  const int quad = lane >> 4;
  const int l16  = lane & 15;
  const int r0   = blockIdx.x * 64 + w * 16;

  const float* Xp = X + (size_t)(r0 + quad) * CC + l16 * 4;
  const f16* Wbase = Wf + (size_t)p * 32 * 4 * 512 + lane * 8;

  f32x4 acc[4];
  #pragma unroll
  for (int nt = 0; nt < 4; ++nt) acc[nt] = (f32x4){0.f, 0.f, 0.f, 0.f};

  f32x4 x0[4], x1[4], x2[4];
  f16x8 w0[2][4], w1[2][4];

  #pragma unroll
  for (int j = 0; j < 4; ++j) {
    x0[j] = *(const f32x4*)(Xp + (size_t)(j * 4) * CC);
    x1[j] = *(const f32x4*)(Xp + (size_t)(j * 4) * CC + 64);
  }
  #pragma unroll
  for (int kk = 0; kk < 2; ++kk)
    #pragma unroll
    for (int nt = 0; nt < 4; ++nt)
      w0[kk][nt] = *(const f16x8*)(Wbase + (size_t)(kk * 4 + nt) * 512);

  #pragma unroll 1
  for (int it = 0; it < 16; ++it) {
    const int buf = it & 1;
    // stage current window (wave-private)
    #pragma unroll
    for (int j = 0; j < 4; ++j) {
      f16x4 h;
      #pragma unroll
      for (int t = 0; t < 4; ++t) h[t] = (f16)x0[j][t];
      *(f16x4*)&As[w][buf][j * 4 + quad][l16 * 4] = h;
    }
    // prefetch W(it+1) and X(it+2), clamped (branch-free)
    const int pw = (it + 1 < 16) ? it + 1 : 15;
    const int px = (it + 2 < 16) ? it + 2 : 15;
    #pragma unroll
    for (int kk = 0; kk < 2; ++kk)
      #pragma unroll
      for (int nt = 0; nt < 4; ++nt)
        w1[kk][nt] = *(const f16x8*)(Wbase + (size_t)((pw * 2 + kk) * 4 + nt) * 512);
    #pragma unroll
    for (int j = 0; j < 4; ++j)
      x2[j] = *(const f32x4*)(Xp + (size_t)(j * 4) * CC + px * 64);
    // compute with w0 / staged buf
    #pragma unroll
    for (int kk = 0; kk < 2; ++kk) {
      f16x8 af = *(const f16x8*)&As[w][buf][l16][kk * 32 + quad * 8];
      #pragma unroll
      for (int nt = 0; nt < 4; ++nt)
        acc[nt] = MFMA32(af, w0[kk][nt], acc[nt]);
    }
    // rotate
    #pragma unroll
    for (int j = 0; j < 4; ++j) { x0[j] = x1[j]; x1[j] = x2[j]; }
    #pragma unroll
    for (int kk = 0; kk < 2; ++kk)
      #pragma unroll
      for (int nt = 0; nt < 4; ++nt)
        w0[kk][nt] = w1[kk][nt];
  }

  // epilogue: acc (C-layout) -> frag-major via wave-private LDS transpose
  f16 (*Ls)[66] = As[w][0];
  #pragma unroll
  for (int nt = 0; nt < 4; ++nt)
    #pragma unroll
    for (int r = 0; r < 4; ++r)
      Ls[quad * 4 + r][nt * 16 + l16] = (f16)acc[nt][r];
  const size_t chunk = (size_t)blockIdx.x * 4 + w;
  if (p < 2) {
    #pragma unroll
    for (int h = 0; h < 2; ++h) {
      f16x8 t = *(const f16x8*)&Ls[l16][h * 32 + quad * 8];
      *(f16x8*)(O + (chunk * 2 + h) * 512 + lane * 8) = t;
    }
  } else {
    #pragma unroll
    for (int np = 0; np < 2; ++np) {
      f16x8 t;
      #pragma unroll
      for (int j = 0; j < 8; ++j)
        t[j] = Ls[quad * 4 + (j & 3)][(2 * np + (j >> 2)) * 16 + l16];
      *(f16x8*)(O + (chunk * 2 + np) * 512 + lane * 8) = t;
    }
  }
}

// ---------------------------------------------------------------------------
// Flash attention, mask s <= t+1. Frag-major coalesced loads; K AND V
// prefetched one step ahead. Scale pre-folded into Wq.
// ---------------------------------------------------------------------------
__device__ __forceinline__ void attn_tile(
    int b, int j, int a, int e, int wave, int quad, int l16, int lane, int sp,
    const f16* __restrict__ Qf, const f16* __restrict__ Kf, const f16* __restrict__ Vf,
    float* __restrict__ Opart, float* __restrict__ lpart)
{
  const int m0 = j * 64 + wave * 16;
  const int e_w = min(e, j + 1 + (wave == 3 ? 1 : 0));

  const f16* Qfb = Qf + (size_t)b * PB_F16;
  const f16* Kfb = Kf + (size_t)b * PB_F16 + lane * 8;
  const f16* Vfb = Vf + (size_t)b * PB_F16 + lane * 8;

  f16x8 qa0 = *(const f16x8*)(Qfb + ((size_t)(m0 >> 4) * 2 + 0) * 512 + lane * 8);
  f16x8 qa1 = *(const f16x8*)(Qfb + ((size_t)(m0 >> 4) * 2 + 1) * 512 + lane * 8);

  f32x4 o[4];
  float lsum = 0.f;
  #pragma unroll
  for (int nt = 0; nt < 4; ++nt) o[nt] = (f32x4){0.f, 0.f, 0.f, 0.f};

  f16x8 kc[8], vc[8];
  int st = a;
  if (st < e_w) {
    const f16* kp = Kfb + (size_t)st * 4 * CHUNK_F16;
    const f16* vp = Vfb + (size_t)st * 4 * CHUNK_F16;
    #pragma unroll
    for (int ct = 0; ct < 4; ++ct) {
      kc[2 * ct]     = *(const f16x8*)(kp + ct * CHUNK_F16);
      kc[2 * ct + 1] = *(const f16x8*)(kp + ct * CHUNK_F16 + 512);
      vc[2 * ct]     = *(const f16x8*)(vp + ct * CHUNK_F16);
      vc[2 * ct + 1] = *(const f16x8*)(vp + ct * CHUNK_F16 + 512);
    }
  }

  while (st < e_w) {
    const int s0 = st * 64;
    // prefetch next step's K and V (in flight during QK+softmax+PV)
    const bool more = (st + 1 < e_w);
    f16x8 kn[8], vn[8];
    if (more) {
      const f16* kp = Kfb + (size_t)(st + 1) * 4 * CHUNK_F16;
      const f16* vp = Vfb + (size_t)(st + 1) * 4 * CHUNK_F16;
      #pragma unroll
      for (int ct = 0; ct < 4; ++ct) {
        kn[2 * ct]     = *(const f16x8*)(kp + ct * CHUNK_F16);
        kn[2 * ct + 1] = *(const f16x8*)(kp + ct * CHUNK_F16 + 512);
        vn[2 * ct]     = *(const f16x8*)(vp + ct * CHUNK_F16);
        vn[2 * ct + 1] = *(const f16x8*)(vp + ct * CHUNK_F16 + 512);
      }
    }

    // S^T = K Q^T (scale pre-folded into Q)
    f32x4 sc[4];
    #pragma unroll
    for (int ct = 0; ct < 4; ++ct) {
      f32x4 z = (f32x4){0.f, 0.f, 0.f, 0.f};
      z = MFMA32(kc[2 * ct], qa0, z);
      sc[ct] = MFMA32(kc[2 * ct + 1], qa1, z);
    }

    // mask + exp2; lane: query=m0+l16, key=s0+ct*16+quad*4+r
    const bool domask = (s0 + 63) > (m0 + 1);
    f16x4 pa[4];
    #pragma unroll
    for (int ct = 0; ct < 4; ++ct) {
      #pragma unroll
      for (int r = 0; r < 4; ++r) {
        float x = sc[ct][r];
        if (domask) {
          const int key = s0 + ct * 16 + quad * 4 + r;
          if (key > m0 + l16 + 1) x = -__builtin_inff();
        }
        const float pv = __builtin_amdgcn_exp2f(x);
        lsum += pv;
        pa[ct][r] = (f16)pv;
      }
    }

    // PV: A=P (MFMA16 A-layout), B=V frag halves
    #pragma unroll
    for (int ct = 0; ct < 4; ++ct) {
      #pragma unroll
      for (int np = 0; np < 2; ++np) {
        f16x4 blo = __builtin_shufflevector(vc[2 * ct + np], vc[2 * ct + np], 0, 1, 2, 3);
        f16x4 bhi = __builtin_shufflevector(vc[2 * ct + np], vc[2 * ct + np], 4, 5, 6, 7);
        o[2 * np]     = MFMA16(pa[ct], blo, o[2 * np]);
        o[2 * np + 1] = MFMA16(pa[ct], bhi, o[2 * np + 1]);
      }
    }

    if (more) {
      #pragma unroll
      for (int i = 0; i < 8; ++i) { kc[i] = kn[i]; vc[i] = vn[i]; }
    }
    ++st;
  }

  lsum += __shfl_xor(lsum, 16, 64);
  lsum += __shfl_xor(lsum, 32, 64);
  const size_t rbase = (size_t)(sp * BB + b) * TT;
  if (quad == 0) lpart[rbase + m0 + l16] = lsum;
  #pragma unroll
  for (int nt = 0; nt < 4; ++nt)
    #pragma unroll
    for (int r = 0; r < 4; ++r)
      Opart[(rbase + m0 + quad * 4 + r) * HH + nt * 16 + l16] = o[nt][r];
}

__global__ __launch_bounds__(256, 3) void attn_kernel(
    const f16* __restrict__ Qf, const f16* __restrict__ Kf, const f16* __restrict__ Vf,
    float* __restrict__ Opart, float* __restrict__ lpart, int S)
{
  const int pr = blockIdx.x;
  const int sp = blockIdx.y;
  const int b  = blockIdx.z;
  const int tid  = threadIdx.x;
  const int wave = tid >> 6;
  const int lane = tid & 63;
  const int quad = lane >> 4;
  const int l16  = lane & 15;

  const int j1 = pr, j2 = 63 - pr;
  const int n1 = min(j1 + 2, 64), n2 = min(j2 + 2, 64);
  const int tot = n1 + n2;
  const int lo = tot * sp / S, hi = tot * (sp + 1) / S;
  const int a1 = min(lo, n1), e1 = min(hi, n1);
  const int a2 = max(lo - n1, 0), e2 = max(hi - n1, 0);

  attn_tile(b, j1, a1, e1, wave, quad, l16, lane, sp, Qf, Kf, Vf, Opart, lpart);
  attn_tile(b, j2, a2, e2, wave, quad, l16, lane, sp, Qf, Kf, Vf, Opart, lpart);
}

// ---------------------------------------------------------------------------
__global__ __launch_bounds__(256) void combine_kernel(
    const float* __restrict__ Opart, const float* __restrict__ lpart,
    float* __restrict__ out, int S)
{
  const int idx = blockIdx.x * 256 + threadIdx.x;
  const int row = idx >> 4;
  const int c   = (idx & 15) * 4;
  float l = 0.f;
  f32x4 s = (f32x4){0.f, 0.f, 0.f, 0.f};
  for (int p = 0; p < S; ++p) {
    l += lpart[(size_t)p * BB * TT + row];
    s += *(const f32x4*)&Opart[((size_t)p * BB * TT + row) * HH + c];
  }
  const float inv = 1.0f / l;
  *(f32x4*)&out[(size_t)row * HH + c] = s * inv;
}

// ---------------------------------------------------------------------------
extern "C" void kernel_launch(void* const* d_in, const int* in_sizes, int n_in,
                              void* d_out, int out_size, void* d_ws, size_t ws_size,
                              hipStream_t stream)
{
  const float* q  = (const float*)d_in[0];
  const float* k  = (const float*)d_in[1];
  const float* v  = (const float*)d_in[2];
  const float* Wq = (const float*)d_in[3];
  const float* Wk = (const float*)d_in[4];
  const float* Wv = (const float*)d_in[5];
  float* out = (float*)d_out;

  const size_t n = (size_t)BB * TT * HH;   // 1,048,576 f16 per tensor
  const size_t need8 = (WF_ELEMS + 3 * n) * sizeof(f16)
                     + 8 * n * sizeof(float) + 8 * (size_t)BB * TT * sizeof(float);
  const int S = (ws_size >= need8) ? 8 : 4;

  f16* Wf = (f16*)d_ws;
  f16* Qf = Wf + WF_ELEMS;
  f16* Kf = Qf + n;
  f16* Vf = Kf + n;
  float* Opart = (float*)(Vf + n);
  float* lpart = Opart + (size_t)S * n;

  wrepack_kernel<<<dim3(384), 64, 0, stream>>>(Wq, Wk, Wv, Wf);
  proj_kernel<<<dim3(256, 3), 256, 0, stream>>>(q, k, v, Wf, Qf, Kf, Vf);
  attn_kernel<<<dim3(32, S, BB), 256, 0, stream>>>(Qf, Kf, Vf, Opart, lpart, S);
  combine_kernel<<<dim3(1024), 256, 0, stream>>>(Opart, lpart, out, S);
}

// Round 6
// 235.547 us; speedup vs baseline: 1.5109x; 1.0433x over previous
//
#include <hip/hip_runtime.h>
#include <hip/hip_bf16.h>

#define BB 4
#define TT 4096
#define CC 1024
#define HH 64

typedef _Float16 f16;
typedef __attribute__((ext_vector_type(8))) _Float16 f16x8;
typedef __attribute__((ext_vector_type(4))) _Float16 f16x4;
typedef __attribute__((ext_vector_type(4))) float f32x4;

#define MFMA32(a,b,c) __builtin_amdgcn_mfma_f32_16x16x32_f16((a),(b),(c),0,0,0)
#define MFMA16(a,b,c) __builtin_amdgcn_mfma_f32_16x16x16f16((a),(b),(c),0,0,0)

// frag-major sizes (f16 units)
#define WF_ELEMS (3 * 32 * 4 * 64 * 8)        // 196,608
#define CHUNK_F16 1024                        // per 16-row chunk: 2 halves x 64 lanes x 8
#define PB_F16 (256 * CHUNK_F16)              // per batch: 256 chunks

// Async global->LDS, 16B per lane. Side-effecting: compiler cannot sink it.
// LDS dest must be wave-uniform; lane i's 16B lands at dest + i*16.
static __device__ __forceinline__ void gl_lds16(const void* g, void* l) {
  __builtin_amdgcn_global_load_lds(
      (const __attribute__((address_space(1))) unsigned int*)g,
      (__attribute__((address_space(3))) unsigned int*)l, 16, 0, 0);
}

static __device__ __forceinline__ f16x8 pack2(f32x4 a, f32x4 b) {
  f16x8 r;
  r[0]=(f16)a[0]; r[1]=(f16)a[1]; r[2]=(f16)a[2]; r[3]=(f16)a[3];
  r[4]=(f16)b[0]; r[5]=(f16)b[1]; r[6]=(f16)b[2]; r[7]=(f16)b[3];
  return r;
}

// ---------------------------------------------------------------------------
// Repack W -> frag-major f16. Block bx = (p*32+kc)*4+nt, 64 threads.
// Softmax double-scale log2(e)/64 folded into Wq.
// ---------------------------------------------------------------------------
__global__ __launch_bounds__(64) void wrepack_kernel(
    const float* __restrict__ Wqg, const float* __restrict__ Wkg,
    const float* __restrict__ Wvg, f16* __restrict__ Wf)
{
  const int bx = blockIdx.x;
  const int nt = bx & 3;
  const int kc = (bx >> 2) & 31;
  const int p  = bx >> 7;
  const float* W = (p == 0) ? Wqg : (p == 1) ? Wkg : Wvg;
  const float sc = (p == 0) ? (1.4426950408889634f / 64.0f) : 1.0f;

  const int lane = threadIdx.x;
  const int l16 = lane & 15, quad = lane >> 4;
  const float* src = W + (size_t)(nt * 16 + l16) * CC + kc * 32 + quad * 8;
  f32x4 a = *(const f32x4*)src;
  f32x4 b = *(const f32x4*)(src + 4);
  f16x8 r;
  #pragma unroll
  for (int j = 0; j < 4; ++j) { r[j] = (f16)(a[j] * sc); r[j + 4] = (f16)(b[j] * sc); }
  *(f16x8*)(Wf + (size_t)bx * 512 + lane * 8) = r;
}

// ---------------------------------------------------------------------------
// Projection: X[16384,1024] fp32 x W^T -> frag-major f16.
// m97-style: double-buffered async global_load_lds staging for X (32 KB/iter
// per block) and W (8 KB/iter, L2-hot). X chunks XOR-swizzled so A-frag
// ds_read_b128s are <=4-way. 48 KB LDS -> 3 blocks/CU, 12 waves/CU.
// ---------------------------------------------------------------------------
__global__ __launch_bounds__(256) void proj_kernel(
    const float* __restrict__ qg, const float* __restrict__ kg, const float* __restrict__ vg,
    const f16* __restrict__ Wf,
    f16* __restrict__ Qf, f16* __restrict__ Kf, f16* __restrict__ Vf)
{
  __shared__ float Xs[2][64][64];     // 32 KB
  __shared__ f16   Ws[2][8][64][8];   // 16 KB

  const float* X; f16* O; const int p = blockIdx.y;
  if (p == 0)      { X = qg; O = Qf; }
  else if (p == 1) { X = kg; O = Kf; }
  else             { X = vg; O = Vf; }

  const int tid  = threadIdx.x;
  const int w    = tid >> 6;
  const int lane = tid & 63;
  const int quad = lane >> 4;
  const int l16  = lane & 15;
  const int r0   = blockIdx.x * 64;

  // X staging: inst s (s=0..3 per wave) covers rows R = w*16+s*4+(lane>>4).
  // Stored phys chunk pc = lane&15 holds logical chunk lc = pc ^ ((R&7)<<1).
  const float* Xrow[4];
  #pragma unroll
  for (int s = 0; s < 4; ++s) {
    const int R  = w * 16 + s * 4 + (lane >> 4);
    const int lc = (lane & 15) ^ ((R & 7) << 1);
    Xrow[s] = X + (size_t)(r0 + R) * CC + lc * 4;
  }
  // W staging: inst j = 2w+jj covers frag-block (it*8 + j), contiguous 8 KB/iter.
  const f16* Wfp = Wf + (size_t)p * 128 * 512;
  const f16* Wsrc[2];
  #pragma unroll
  for (int jj = 0; jj < 2; ++jj)
    Wsrc[jj] = Wfp + (size_t)(2 * w + jj) * 512 + lane * 8;

  f32x4 acc[4];
  #pragma unroll
  for (int nt = 0; nt < 4; ++nt) acc[nt] = (f32x4){0.f, 0.f, 0.f, 0.f};

  // initial stage: it=0 -> buf 0
  #pragma unroll
  for (int s = 0; s < 4; ++s)
    gl_lds16(Xrow[s], &Xs[0][w * 16 + s * 4][0]);
  #pragma unroll
  for (int jj = 0; jj < 2; ++jj)
    gl_lds16(Wsrc[jj], &Ws[0][2 * w + jj][0][0]);

  const int sw = (l16 & 7) << 1;   // frag-read swizzle (R&7 == l16&7 for row w*16+l16)

  for (int it = 0; it < 16; ++it) {
    const int buf = it & 1;
    __syncthreads();   // vmcnt(0) drains staging of buf; joins prev compute
    if (it < 15) {
      #pragma unroll
      for (int s = 0; s < 4; ++s)
        gl_lds16(Xrow[s] + (it + 1) * 64, &Xs[buf ^ 1][w * 16 + s * 4][0]);
      #pragma unroll
      for (int jj = 0; jj < 2; ++jj)
        gl_lds16(Wsrc[jj] + (size_t)(it + 1) * 4096, &Ws[buf ^ 1][2 * w + jj][0][0]);
    }
    #pragma unroll
    for (int kk = 0; kk < 2; ++kk) {
      const int c0 = kk * 8 + quad * 2;
      f32x4 a0 = *(const f32x4*)&Xs[buf][w * 16 + l16][(c0 ^ sw) * 4];
      f32x4 a1 = *(const f32x4*)&Xs[buf][w * 16 + l16][((c0 + 1) ^ sw) * 4];
      f16x8 af = pack2(a0, a1);
      #pragma unroll
      for (int nt = 0; nt < 4; ++nt) {
        f16x8 bf = *(const f16x8*)&Ws[buf][kk * 4 + nt][lane][0];
        acc[nt] = MFMA32(af, bf, acc[nt]);
      }
    }
  }

  // epilogue: C-layout acc -> frag-major via wave-private LDS region.
  // Xs[0] rows w*16..w*16+15 (4 KB/wave) are free: last read was it=14,
  // protected by it=15's barrier. No extra barrier needed (wave-private).
  f16 (*Ls)[66] = (f16(*)[66])&Xs[0][w * 16][0];
  #pragma unroll
  for (int nt = 0; nt < 4; ++nt)
    #pragma unroll
    for (int r = 0; r < 4; ++r)
      Ls[quad * 4 + r][nt * 16 + l16] = (f16)acc[nt][r];
  const size_t chunk = (size_t)blockIdx.x * 4 + w;
  if (p < 2) {
    // Q/K frag: [chunk][half][lane][8] = tile[row=l16][hd=32h+8q+j]
    #pragma unroll
    for (int h = 0; h < 2; ++h) {
      f16x8 t = *(const f16x8*)&Ls[l16][h * 32 + quad * 8];
      *(f16x8*)(O + (chunk * 2 + h) * 512 + lane * 8) = t;
    }
  } else {
    // V frag: [chunk][np][lane][8] = tile[key=4q+(j&3)][hd=(2np+(j>>2))*16+l16]
    #pragma unroll
    for (int np = 0; np < 2; ++np) {
      f16x8 t;
      #pragma unroll
      for (int j = 0; j < 8; ++j)
        t[j] = Ls[quad * 4 + (j & 3)][(2 * np + (j >> 2)) * 16 + l16];
      *(f16x8*)(O + (chunk * 2 + np) * 512 + lane * 8) = t;
    }
  }
}

// ---------------------------------------------------------------------------
// Flash attention, mask s <= t+1. Block-wide double-buffered async staging of
// K and V steps (each step = contiguous 8 KB in frag-major layout). Frag reads
// are lane-linear ds_read_b128 (conflict-free). Uniform trip counts.
// S^T via MFMA(A=K,B=Q); P C-layout == MFMA16 A-layout. Scale folded into Wq.
// ---------------------------------------------------------------------------
__device__ __forceinline__ void attn_tile(
    int b, int j, int a, int e, int wave, int quad, int l16, int lane, int sp,
    const f16* __restrict__ Qf, const f16* __restrict__ Kf, const f16* __restrict__ Vf,
    f16 (*Ks)[8][64][8], f16 (*Vs)[8][64][8],
    float* __restrict__ Opart, float* __restrict__ lpart)
{
  const int m0 = j * 64 + wave * 16;

  const f16* Kfb = Kf + (size_t)b * PB_F16;
  const f16* Vfb = Vf + (size_t)b * PB_F16;
  const f16* Qfb = Qf + (size_t)b * PB_F16;

  f16x8 qa0 = *(const f16x8*)(Qfb + ((size_t)(m0 >> 4) * 2 + 0) * 512 + lane * 8);
  f16x8 qa1 = *(const f16x8*)(Qfb + ((size_t)(m0 >> 4) * 2 + 1) * 512 + lane * 8);

  f32x4 o[4];
  float lsum = 0.f;
  #pragma unroll
  for (int nt = 0; nt < 4; ++nt) o[nt] = (f32x4){0.f, 0.f, 0.f, 0.f};

  // protect staging buffers from the previous tile's laggard readers
  __syncthreads();

  if (a < e) {
    #pragma unroll
    for (int jj = 0; jj < 2; ++jj) {
      const int idx = 2 * wave + jj;
      gl_lds16(Kfb + (size_t)a * 4096 + idx * 512 + lane * 8, &Ks[0][idx][0][0]);
      gl_lds16(Vfb + (size_t)a * 4096 + idx * 512 + lane * 8, &Vs[0][idx][0][0]);
    }
  }

  for (int st = a; st < e; ++st) {
    const int buf = (st - a) & 1;
    __syncthreads();   // drains staging of buf
    if (st + 1 < e) {
      #pragma unroll
      for (int jj = 0; jj < 2; ++jj) {
        const int idx = 2 * wave + jj;
        gl_lds16(Kfb + (size_t)(st + 1) * 4096 + idx * 512 + lane * 8, &Ks[buf ^ 1][idx][0][0]);
        gl_lds16(Vfb + (size_t)(st + 1) * 4096 + idx * 512 + lane * 8, &Vs[buf ^ 1][idx][0][0]);
      }
    }
    const int s0 = st * 64;

    // S^T = K Q^T (scale pre-folded into Q)
    f32x4 sc[4];
    #pragma unroll
    for (int ct = 0; ct < 4; ++ct) {
      f16x8 k0 = *(const f16x8*)&Ks[buf][ct * 2][lane][0];
      f16x8 k1 = *(const f16x8*)&Ks[buf][ct * 2 + 1][lane][0];
      f32x4 z = (f32x4){0.f, 0.f, 0.f, 0.f};
      z = MFMA32(k0, qa0, z);
      sc[ct] = MFMA32(k1, qa1, z);
    }

    // mask + exp2; lane: query=m0+l16, key=s0+ct*16+quad*4+r
    const bool domask = (s0 + 63) > (m0 + 1);
    f16x4 pa[4];
    #pragma unroll
    for (int ct = 0; ct < 4; ++ct) {
      #pragma unroll
      for (int r = 0; r < 4; ++r) {
        float x = sc[ct][r];
        if (domask) {
          const int key = s0 + ct * 16 + quad * 4 + r;
          if (key > m0 + l16 + 1) x = -__builtin_inff();
        }
        const float pv = __builtin_amdgcn_exp2f(x);
        lsum += pv;
        pa[ct][r] = (f16)pv;
      }
    }

    // PV: A=P (MFMA16 A-layout), B=V frag halves
    #pragma unroll
    for (int ct = 0; ct < 4; ++ct) {
      #pragma unroll
      for (int np = 0; np < 2; ++np) {
        f16x8 vv = *(const f16x8*)&Vs[buf][ct * 2 + np][lane][0];
        f16x4 blo = __builtin_shufflevector(vv, vv, 0, 1, 2, 3);
        f16x4 bhi = __builtin_shufflevector(vv, vv, 4, 5, 6, 7);
        o[2 * np]     = MFMA16(pa[ct], blo, o[2 * np]);
        o[2 * np + 1] = MFMA16(pa[ct], bhi, o[2 * np + 1]);
      }
    }
  }

  lsum += __shfl_xor(lsum, 16, 64);
  lsum += __shfl_xor(lsum, 32, 64);
  const size_t rbase = (size_t)(sp * BB + b) * TT;
  if (quad == 0) lpart[rbase + m0 + l16] = lsum;
  #pragma unroll
  for (int nt = 0; nt < 4; ++nt)
    #pragma unroll
    for (int r = 0; r < 4; ++r)
      Opart[(rbase + m0 + quad * 4 + r) * HH + nt * 16 + l16] = o[nt][r];
}

__global__ __launch_bounds__(256) void attn_kernel(
    const f16* __restrict__ Qf, const f16* __restrict__ Kf, const f16* __restrict__ Vf,
    float* __restrict__ Opart, float* __restrict__ lpart, int S)
{
  __shared__ f16 Ks[2][8][64][8];   // 16 KB
  __shared__ f16 Vs[2][8][64][8];   // 16 KB

  const int pr = blockIdx.x;
  const int sp = blockIdx.y;
  const int b  = blockIdx.z;
  const int tid  = threadIdx.x;
  const int wave = tid >> 6;
  const int lane = tid & 63;
  const int quad = lane >> 4;
  const int l16  = lane & 15;

  const int j1 = pr, j2 = 63 - pr;
  const int n1 = min(j1 + 2, 64), n2 = min(j2 + 2, 64);
  const int tot = n1 + n2;
  const int lo = tot * sp / S, hi = tot * (sp + 1) / S;
  const int a1 = min(lo, n1), e1 = min(hi, n1);
  const int a2 = max(lo - n1, 0), e2 = max(hi - n1, 0);

  attn_tile(b, j1, a1, e1, wave, quad, l16, lane, sp, Qf, Kf, Vf, Ks, Vs, Opart, lpart);
  attn_tile(b, j2, a2, e2, wave, quad, l16, lane, sp, Qf, Kf, Vf, Ks, Vs, Opart, lpart);
}

// ---------------------------------------------------------------------------
// Combine S split partials: out = sum_s O_s / sum_s l_s
// ---------------------------------------------------------------------------
__global__ __launch_bounds__(256) void combine_kernel(
    const float* __restrict__ Opart, const float* __restrict__ lpart,
    float* __restrict__ out, int S)
{
  const int idx = blockIdx.x * 256 + threadIdx.x;
  const int row = idx >> 4;
  const int c   = (idx & 15) * 4;
  float l = 0.f;
  f32x4 s = (f32x4){0.f, 0.f, 0.f, 0.f};
  for (int p = 0; p < S; ++p) {
    l += lpart[(size_t)p * BB * TT + row];
    s += *(const f32x4*)&Opart[((size_t)p * BB * TT + row) * HH + c];
  }
  const float inv = 1.0f / l;
  *(f32x4*)&out[(size_t)row * HH + c] = s * inv;
}

// ---------------------------------------------------------------------------
extern "C" void kernel_launch(void* const* d_in, const int* in_sizes, int n_in,
                              void* d_out, int out_size, void* d_ws, size_t ws_size,
                              hipStream_t stream)
{
  const float* q  = (const float*)d_in[0];
  const float* k  = (const float*)d_in[1];
  const float* v  = (const float*)d_in[2];
  const float* Wq = (const float*)d_in[3];
  const float* Wk = (const float*)d_in[4];
  const float* Wv = (const float*)d_in[5];
  float* out = (float*)d_out;

  const size_t n = (size_t)BB * TT * HH;   // 1,048,576 f16 per tensor
  const size_t need8 = (WF_ELEMS + 3 * n) * sizeof(f16)
                     + 8 * n * sizeof(float) + 8 * (size_t)BB * TT * sizeof(float);
  const int S = (ws_size >= need8) ? 8 : 4;

  f16* Wf = (f16*)d_ws;
  f16* Qf = Wf + WF_ELEMS;
  f16* Kf = Qf + n;
  f16* Vf = Kf + n;
  float* Opart = (float*)(Vf + n);
  float* lpart = Opart + (size_t)S * n;

  wrepack_kernel<<<dim3(384), 64, 0, stream>>>(Wq, Wk, Wv, Wf);
  proj_kernel<<<dim3(256, 3), 256, 0, stream>>>(q, k, v, Wf, Qf, Kf, Vf);
  attn_kernel<<<dim3(32, S, BB), 256, 0, stream>>>(Qf, Kf, Vf, Opart, lpart, S);
  combine_kernel<<<dim3(1024), 256, 0, stream>>>(Opart, lpart, out, S);
}